// Round 8
// baseline (128.389 us; speedup 1.0000x reference)
//
#include <hip/hip_runtime.h>

#define HW 28
#define NPIX 784
#define NIMG 512
#define NBLK 256                 // 2 images per block
#define PR 34                    // padded rows: -3..30
#define PC 52                    // padded row stride in halfs (104 B)
#define PLANE (PR * PC)          // 1768 halfs per plane

typedef _Float16 half8 __attribute__((ext_vector_type(8)));
typedef float    f32x4 __attribute__((ext_vector_type(4)));

union H8 { unsigned short s[8]; uint2 u2[2]; half8 h; };

// ---------------------------------------------------------------------------
// r24: r23 kernel + CALIBRATED SPIN PROBE (diagnostic round).
// Seven structurally different kernels all measure 40-46us with every pipe
// <35% busy; bottom-up cycle audits say 15-25k cycles but 40us @2.4GHz =
// 95k. Discriminate {low DVFS clock} vs {coverable stall slack} vs {real
// serialization}: a data-independent dependent chain of 6000 v_fma_f32
// (= 24k cycles = 10.0us @ 2.4GHz) added to EVERY wave. Output unchanged.
// Read: +10us => full clock, no slack. +20-45us => low clock (cycle floor
// reached, revert+stop). +0-4us => full clock w/ >=10us coverable stall
// (pipeline harder next). VALUBusy must rise (else DCE'd).
// ---------------------------------------------------------------------------
__device__ __forceinline__ void mconv2(const _Float16 (*ev0)[PC], const _Float16 (*pv0)[PC],
                                       const _Float16 (*ev1)[PC], const _Float16 (*pv1)[PC],
                                       const unsigned short (*tbl)[7][48], // [wt][di][pos]
                                       int q, int n15, f32x4 o[2][2][2])   // [img][rt][ct]
{
    f32x4 num[2][2][2], den[2][2][2];
#pragma unroll
    for (int i = 0; i < 2; ++i)
#pragma unroll
        for (int a = 0; a < 2; ++a)
#pragma unroll
            for (int c = 0; c < 2; ++c) {
                num[i][a][c] = (f32x4){0.f, 0.f, 0.f, 0.f};
                den[i][a][c] = (f32x4){0.f, 0.f, 0.f, 0.f};
            }

    const int bp = 16 + 4 * q - n15;        // table base position, in [1,28]

#pragma unroll
    for (int di = 0; di < 7; ++di) {
        H8 bq, be;
        const unsigned short* tq = &tbl[0][di][0];
        const unsigned short* te = &tbl[1][di][0];
#pragma unroll
        for (int j = 0; j < 4; ++j) {       // k-slots: 0..3 -> 4q+j, 4..7 -> 16+4q+j
            bq.s[j]     = tq[bp + j];
            bq.s[4 + j] = tq[bp + 16 + j];
            be.s[j]     = te[bp + j];
            be.s[4 + j] = te[bp + 16 + j];
        }
#pragma unroll
        for (int rt = 0; rt < 2; ++rt) {
            const int row = rt * 12 + di + n15;          // <= 33
#pragma unroll
            for (int ct = 0; ct < 2; ++ct) {
                const int col = ct * 16 + 4 * q;         // 8B-aligned (104B rows)
                H8 ea0, pa0, ea1, pa1;
                ea0.u2[0] = *(const uint2*)&ev0[row][col];
                ea0.u2[1] = *(const uint2*)&ev0[row][col + 16];
                pa0.u2[0] = *(const uint2*)&pv0[row][col];
                pa0.u2[1] = *(const uint2*)&pv0[row][col + 16];
                ea1.u2[0] = *(const uint2*)&ev1[row][col];
                ea1.u2[1] = *(const uint2*)&ev1[row][col + 16];
                pa1.u2[0] = *(const uint2*)&pv1[row][col];
                pa1.u2[1] = *(const uint2*)&pv1[row][col + 16];
                num[0][rt][ct] = __builtin_amdgcn_mfma_f32_16x16x32_f16(ea0.h, bq.h, num[0][rt][ct], 0, 0, 0);
                num[1][rt][ct] = __builtin_amdgcn_mfma_f32_16x16x32_f16(ea1.h, bq.h, num[1][rt][ct], 0, 0, 0);
                num[0][rt][ct] = __builtin_amdgcn_mfma_f32_16x16x32_f16(pa0.h, be.h, num[0][rt][ct], 0, 0, 0);
                num[1][rt][ct] = __builtin_amdgcn_mfma_f32_16x16x32_f16(pa1.h, be.h, num[1][rt][ct], 0, 0, 0);
                den[0][rt][ct] = __builtin_amdgcn_mfma_f32_16x16x32_f16(ea0.h, be.h, den[0][rt][ct], 0, 0, 0);
                den[1][rt][ct] = __builtin_amdgcn_mfma_f32_16x16x32_f16(ea1.h, be.h, den[1][rt][ct], 0, 0, 0);
            }
        }
    }
#pragma unroll
    for (int i = 0; i < 2; ++i)
#pragma unroll
        for (int a = 0; a < 2; ++a)
#pragma unroll
            for (int c = 0; c < 2; ++c)
#pragma unroll
                for (int v = 0; v < 4; ++v)
                    o[i][a][c][v] = num[i][a][c][v] * __builtin_amdgcn_rcpf(den[i][a][c][v]);
}

__device__ __forceinline__ float sigmoidf_(float s) {
    return __builtin_amdgcn_rcpf(1.f + __expf(-s));
}

__global__ __launch_bounds__(512, 1) void smorph_net_kernel(
    const float* __restrict__ x,       // [512,784]
    const float* __restrict__ sw,      // [8,2,49]
    const float* __restrict__ sa,      // [8,2]
    const float* __restrict__ W1, const float* __restrict__ b1,
    const float* __restrict__ W2, const float* __restrict__ b2,
    const float* __restrict__ W3, const float* __restrict__ b3,
    float* __restrict__ out)           // [512,10]
{
    __shared__ __align__(16) _Float16       planes[8][2][2][PR][PC]; // 113,152 B
    __shared__ __align__(16) unsigned short wtbl[8][2][7][48];       //  10,752 B
    __shared__ __align__(16) float          mlp2[2][640];            //   5,120 B

    const int b0   = blockIdx.x * 2;   // image pair
    const int tid  = threadIdx.x;
    const int f    = tid >> 6;
    const int lane = tid & 63;
    const int n15  = lane & 15;
    const int q    = lane >> 4;

    _Float16 (*ev0)[PC] = planes[f][0][0];
    _Float16 (*pv0)[PC] = planes[f][0][1];
    _Float16 (*ev1)[PC] = planes[f][1][0];
    _Float16 (*pv1)[PC] = planes[f][1][1];
    const float* src0 = x + (size_t)b0 * NPIX;
    const float* src1 = src0 + NPIX;

    const float a1 = sa[f * 2 + 0];
    const float a2 = sa[f * 2 + 1];

    unsigned wp1 = 0, wp2 = 0;
    if (lane < 49) {
        union { _Float16 h[2]; unsigned u; } p;
        float w1v = sw[(f * 2 + 0) * 49 + lane];
        float e1  = __expf(a1 * w1v);
        p.h[0] = (_Float16)(w1v * e1);
        p.h[1] = (_Float16)e1;
        wp1 = p.u;
        float w2v = sw[(f * 2 + 1) * 49 + lane];
        float e2  = __expf(a2 * w2v);
        p.h[0] = (_Float16)(w2v * e2);
        p.h[1] = (_Float16)e2;
        wp2 = p.u;
    }

    {
        unsigned* tz = (unsigned*)&wtbl[f][0][0][0];   // 336 uints
        for (int i = lane; i < 336; i += 64) tz[i] = 0;
    }
    if (lane < 49) {
        int di = lane / 7, t = lane - di * 7;
        wtbl[f][0][di][16 + t] = (unsigned short)(wp1 & 0xFFFF);   // qw
        wtbl[f][1][di][16 + t] = (unsigned short)(wp1 >> 16);      // ew
    }

    {
        unsigned* e0u = (unsigned*)&planes[f][0][0][0][0];
        unsigned* p0u = (unsigned*)&planes[f][0][1][0][0];
        unsigned* e1u = (unsigned*)&planes[f][1][0][0][0];
        unsigned* p1u = (unsigned*)&planes[f][1][1][0][0];
        for (int i = lane; i < PLANE / 2; i += 64) {
            e0u[i] = 0x3C003C00u; p0u[i] = 0u;
            e1u[i] = 0x3C003C00u; p1u[i] = 0u;
        }
    }

#pragma unroll
    for (int k = 0; k < 13; ++k) {
        int p = lane + 64 * k;
        if (p < NPIX) {
            float v0 = src0[p];
            float v1 = src1[p];
            int pi = p / HW;
            int pj = p - pi * HW;
            float e0 = __expf(a1 * v0);
            float e1 = __expf(a1 * v1);
            ev0[pi + 3][pj + 3] = (_Float16)e0;
            pv0[pi + 3][pj + 3] = (_Float16)(v0 * e0);
            ev1[pi + 3][pj + 3] = (_Float16)e1;
            pv1[pi + 3][pj + 3] = (_Float16)(v1 * e1);
        }
    }

    // ===== CALIBRATED SPIN PROBE: 6000 dependent v_fma_f32 = 24k cycles =====
    // Data-independent of everything below; sunk via asm; output unchanged.
    {
        float z  = a1 * 1.0000001f + (float)lane * 1e-8f;   // runtime, non-hoistable
        float zb = 0.99999988f;
        float zc = 1.0e-20f;
#pragma unroll 1
        for (int it = 0; it < 750; ++it) {
#pragma unroll
            for (int u = 0; u < 8; ++u)
                asm volatile("v_fma_f32 %0, %0, %1, %2"
                             : "+v"(z) : "v"(zb), "v"(zc));
        }
        asm volatile("" :: "v"(z));    // keep alive, no store
    }
    // ========================================================================

    // ---- stage 1 conv (MFMA, both images) ----
    f32x4 o1_[2][2][2];
    mconv2(ev0, pv0, ev1, pv1, wtbl[f], q, n15, o1_);

#pragma unroll
    for (int rt = 0; rt < 2; ++rt)
#pragma unroll
        for (int ct = 0; ct < 2; ++ct) {
            if (ct == 1 && n15 >= 12) continue;
#pragma unroll
            for (int v = 0; v < 4; ++v) {
                int row = rt * 12 + 4 * q + v;
                int col = ct * 16 + n15;
                float ova = o1_[0][rt][ct][v];
                float ovb = o1_[1][rt][ct][v];
                float ea  = __expf(a2 * ova);
                float eb  = __expf(a2 * ovb);
                ev0[row + 3][col + 3] = (_Float16)ea;
                pv0[row + 3][col + 3] = (_Float16)(ova * ea);
                ev1[row + 3][col + 3] = (_Float16)eb;
                pv1[row + 3][col + 3] = (_Float16)(ovb * eb);
            }
        }

    if (lane < 49) {
        int di = lane / 7, t = lane - di * 7;
        wtbl[f][0][di][16 + t] = (unsigned short)(wp2 & 0xFFFF);
        wtbl[f][1][di][16 + t] = (unsigned short)(wp2 >> 16);
    }

    // ---- stage 2 conv (MFMA, both images) ----
    f32x4 o2_[2][2][2];
    mconv2(ev0, pv0, ev1, pv1, wtbl[f], q, n15, o2_);

    float* feat0 = mlp2[0];
    float* feat1 = mlp2[1];

#pragma unroll
    for (int rt = 0; rt < 2; ++rt)
#pragma unroll
        for (int ct = 0; ct < 2; ++ct) {
            float s0 = o2_[0][rt][ct][0] + o2_[0][rt][ct][1] + o2_[0][rt][ct][2] + o2_[0][rt][ct][3];
            float s1 = o2_[1][rt][ct][0] + o2_[1][rt][ct][1] + o2_[1][rt][ct][2] + o2_[1][rt][ct][3];
            s0 += __shfl_xor(s0, 1);  s1 += __shfl_xor(s1, 1);
            s0 += __shfl_xor(s0, 2);  s1 += __shfl_xor(s1, 2);
            int pr = rt ? (3 + q) : q;
            int pc = (ct ? 4 : 0) + (n15 >> 2);
            bool ok = ((n15 & 3) == 0)
                   && !(rt == 1 && q == 0)
                   && !(ct == 1 && n15 >= 12);
            if (ok) {
                feat0[f * 49 + pr * 7 + pc] = s0 * 0.0625f;
                feat1[f * 49 + pr * 7 + pc] = s1 * 0.0625f;
            }
        }
    __syncthreads();

    float* h1_0 = mlp2[0] + 392;  float* h2_0 = mlp2[0] + 512;
    float* h1_1 = mlp2[1] + 392;  float* h2_1 = mlp2[1] + 512;

    if (tid < 480) {
        int n = tid >> 2, h = tid & 3;
        const float4* wr = (const float4*)(W1 + n * 392);
        const float4* f0 = (const float4*)feat0;
        const float4* f1 = (const float4*)feat1;
        float a00 = 0.f, a01 = 0.f, a02 = 0.f, a03 = 0.f;
        float a10 = 0.f, a11 = 0.f, a12 = 0.f, a13 = 0.f;
        for (int k = h; k < 98; k += 4) {
            float4 w  = wr[k];
            float4 u0 = f0[k];
            float4 u1 = f1[k];
            a00 = fmaf(w.x, u0.x, a00);  a10 = fmaf(w.x, u1.x, a10);
            a01 = fmaf(w.y, u0.y, a01);  a11 = fmaf(w.y, u1.y, a11);
            a02 = fmaf(w.z, u0.z, a02);  a12 = fmaf(w.z, u1.z, a12);
            a03 = fmaf(w.w, u0.w, a03);  a13 = fmaf(w.w, u1.w, a13);
        }
        float acc0 = (a00 + a01) + (a02 + a03);
        float acc1 = (a10 + a11) + (a12 + a13);
        acc0 += __shfl_xor(acc0, 1);  acc1 += __shfl_xor(acc1, 1);
        acc0 += __shfl_xor(acc0, 2);  acc1 += __shfl_xor(acc1, 2);
        if (h == 0) {
            h1_0[n] = sigmoidf_(acc0 + b1[n]);
            h1_1[n] = sigmoidf_(acc1 + b1[n]);
        }
    }
    __syncthreads();

    if (tid < 336) {
        int n = tid >> 2, h = tid & 3;
        const float4* wr = (const float4*)(W2 + n * 120);
        const float4* v0 = (const float4*)h1_0;
        const float4* v1 = (const float4*)h1_1;
        float a00 = 0.f, a01 = 0.f, a02 = 0.f, a03 = 0.f;
        float a10 = 0.f, a11 = 0.f, a12 = 0.f, a13 = 0.f;
        for (int k = h; k < 30; k += 4) {
            float4 w  = wr[k];
            float4 u0 = v0[k];
            float4 u1 = v1[k];
            a00 = fmaf(w.x, u0.x, a00);  a10 = fmaf(w.x, u1.x, a10);
            a01 = fmaf(w.y, u0.y, a01);  a11 = fmaf(w.y, u1.y, a11);
            a02 = fmaf(w.z, u0.z, a02);  a12 = fmaf(w.z, u1.z, a12);
            a03 = fmaf(w.w, u0.w, a03);  a13 = fmaf(w.w, u1.w, a13);
        }
        float acc0 = (a00 + a01) + (a02 + a03);
        float acc1 = (a10 + a11) + (a12 + a13);
        acc0 += __shfl_xor(acc0, 1);  acc1 += __shfl_xor(acc1, 1);
        acc0 += __shfl_xor(acc0, 2);  acc1 += __shfl_xor(acc1, 2);
        if (h == 0) {
            h2_0[n] = sigmoidf_(acc0 + b2[n]);
            h2_1[n] = sigmoidf_(acc1 + b2[n]);
        }
    }
    __syncthreads();

    if (tid < 40) {
        int n = tid >> 2, qh = tid & 3;
        const float4* wr = (const float4*)(W3 + n * 84);
        const float4* v0 = (const float4*)h2_0;
        const float4* v1 = (const float4*)h2_1;
        float a00 = 0.f, a01 = 0.f, a02 = 0.f, a03 = 0.f;
        float a10 = 0.f, a11 = 0.f, a12 = 0.f, a13 = 0.f;
        for (int k = qh; k < 21; k += 4) {
            float4 w  = wr[k];
            float4 u0 = v0[k];
            float4 u1 = v1[k];
            a00 = fmaf(w.x, u0.x, a00);  a10 = fmaf(w.x, u1.x, a10);
            a01 = fmaf(w.y, u0.y, a01);  a11 = fmaf(w.y, u1.y, a11);
            a02 = fmaf(w.z, u0.z, a02);  a12 = fmaf(w.z, u1.z, a12);
            a03 = fmaf(w.w, u0.w, a03);  a13 = fmaf(w.w, u1.w, a13);
        }
        float acc0 = (a00 + a01) + (a02 + a03);
        float acc1 = (a10 + a11) + (a12 + a13);
        acc0 += __shfl_xor(acc0, 1);  acc1 += __shfl_xor(acc1, 1);
        acc0 += __shfl_xor(acc0, 2);  acc1 += __shfl_xor(acc1, 2);
        if (qh == 0) {
            out[(size_t)b0 * 10 + n]       = sigmoidf_(acc0 + b3[n]);
            out[(size_t)(b0 + 1) * 10 + n] = sigmoidf_(acc1 + b3[n]);
        }
    }
}

extern "C" void kernel_launch(void* const* d_in, const int* in_sizes, int n_in,
                              void* d_out, int out_size, void* d_ws, size_t ws_size,
                              hipStream_t stream) {
    const float* x  = (const float*)d_in[0];
    const float* sw = (const float*)d_in[1];
    const float* sa = (const float*)d_in[2];
    const float* W1 = (const float*)d_in[3];
    const float* b1 = (const float*)d_in[4];
    const float* W2 = (const float*)d_in[5];
    const float* b2 = (const float*)d_in[6];
    const float* W3 = (const float*)d_in[7];
    const float* b3 = (const float*)d_in[8];
    float* out = (float*)d_out;

    smorph_net_kernel<<<NBLK, 512, 0, stream>>>(x, sw, sa, W1, b1, W2, b2, W3, b3, out);
}

// Round 9
// 96.514 us; speedup vs baseline: 1.3303x; 1.3303x over previous
//
#include <hip/hip_runtime.h>

#define HW 28
#define NPIX 784
#define NIMG 512
#define NBLK 256                 // 2 images per block
#define PR 34                    // padded rows: -3..30
#define PC 52                    // padded row stride in halfs (104 B)
#define PLANE (PR * PC)          // 1768 halfs per plane

typedef _Float16 half8 __attribute__((ext_vector_type(8)));
typedef float    f32x4 __attribute__((ext_vector_type(4)));

union H8 { unsigned short s[8]; uint2 u2[2]; half8 h; };

// ---------------------------------------------------------------------------
// r25: r23 (MFMA, 2 img/block) + W1 REGISTER PREFETCH hoisted under conv1.
// r24 spin probe: +26us for a 6000-dep-FMA chain => effective clock ~1.4GHz
// (not 2.4); per-block time is ONE serial phase chain (~56k cyc); parallel
// work absorbs into it (r23's 2nd image was free), dependent work extends it
// (spin added fully). Wall-clock == chain length. This round removes the
// last known hideable latency: the W1 load chain (~25 L2/L3 loads in the
// serial MLP tail) is issued into registers before conv1 (vmcnt is in-order,
// pack's waits don't drain younger loads; conv1 covers the latency).
// Pre-commit: VGPR must rise to ~200 (else loads sank, void); null result
// (total ~101-103us) => chain is conv-internal at DVFS clock => ROOFLINE.
// ---------------------------------------------------------------------------
__device__ __forceinline__ void mconv2(const _Float16 (*ev0)[PC], const _Float16 (*pv0)[PC],
                                       const _Float16 (*ev1)[PC], const _Float16 (*pv1)[PC],
                                       const unsigned short (*tbl)[7][48], // [wt][di][pos]
                                       int q, int n15, f32x4 o[2][2][2])   // [img][rt][ct]
{
    f32x4 num[2][2][2], den[2][2][2];
#pragma unroll
    for (int i = 0; i < 2; ++i)
#pragma unroll
        for (int a = 0; a < 2; ++a)
#pragma unroll
            for (int c = 0; c < 2; ++c) {
                num[i][a][c] = (f32x4){0.f, 0.f, 0.f, 0.f};
                den[i][a][c] = (f32x4){0.f, 0.f, 0.f, 0.f};
            }

    const int bp = 16 + 4 * q - n15;        // table base position, in [1,28]

#pragma unroll
    for (int di = 0; di < 7; ++di) {
        H8 bq, be;
        const unsigned short* tq = &tbl[0][di][0];
        const unsigned short* te = &tbl[1][di][0];
#pragma unroll
        for (int j = 0; j < 4; ++j) {       // k-slots: 0..3 -> 4q+j, 4..7 -> 16+4q+j
            bq.s[j]     = tq[bp + j];
            bq.s[4 + j] = tq[bp + 16 + j];
            be.s[j]     = te[bp + j];
            be.s[4 + j] = te[bp + 16 + j];
        }
#pragma unroll
        for (int rt = 0; rt < 2; ++rt) {
            const int row = rt * 12 + di + n15;          // <= 33
#pragma unroll
            for (int ct = 0; ct < 2; ++ct) {
                const int col = ct * 16 + 4 * q;         // 8B-aligned (104B rows)
                H8 ea0, pa0, ea1, pa1;
                ea0.u2[0] = *(const uint2*)&ev0[row][col];
                ea0.u2[1] = *(const uint2*)&ev0[row][col + 16];
                pa0.u2[0] = *(const uint2*)&pv0[row][col];
                pa0.u2[1] = *(const uint2*)&pv0[row][col + 16];
                ea1.u2[0] = *(const uint2*)&ev1[row][col];
                ea1.u2[1] = *(const uint2*)&ev1[row][col + 16];
                pa1.u2[0] = *(const uint2*)&pv1[row][col];
                pa1.u2[1] = *(const uint2*)&pv1[row][col + 16];
                num[0][rt][ct] = __builtin_amdgcn_mfma_f32_16x16x32_f16(ea0.h, bq.h, num[0][rt][ct], 0, 0, 0);
                num[1][rt][ct] = __builtin_amdgcn_mfma_f32_16x16x32_f16(ea1.h, bq.h, num[1][rt][ct], 0, 0, 0);
                num[0][rt][ct] = __builtin_amdgcn_mfma_f32_16x16x32_f16(pa0.h, be.h, num[0][rt][ct], 0, 0, 0);
                num[1][rt][ct] = __builtin_amdgcn_mfma_f32_16x16x32_f16(pa1.h, be.h, num[1][rt][ct], 0, 0, 0);
                den[0][rt][ct] = __builtin_amdgcn_mfma_f32_16x16x32_f16(ea0.h, be.h, den[0][rt][ct], 0, 0, 0);
                den[1][rt][ct] = __builtin_amdgcn_mfma_f32_16x16x32_f16(ea1.h, be.h, den[1][rt][ct], 0, 0, 0);
            }
        }
    }
#pragma unroll
    for (int i = 0; i < 2; ++i)
#pragma unroll
        for (int a = 0; a < 2; ++a)
#pragma unroll
            for (int c = 0; c < 2; ++c)
#pragma unroll
                for (int v = 0; v < 4; ++v)
                    o[i][a][c][v] = num[i][a][c][v] * __builtin_amdgcn_rcpf(den[i][a][c][v]);
}

__device__ __forceinline__ float sigmoidf_(float s) {
    return __builtin_amdgcn_rcpf(1.f + __expf(-s));
}

__global__ __launch_bounds__(512, 1) void smorph_net_kernel(
    const float* __restrict__ x,       // [512,784]
    const float* __restrict__ sw,      // [8,2,49]
    const float* __restrict__ sa,      // [8,2]
    const float* __restrict__ W1, const float* __restrict__ b1,
    const float* __restrict__ W2, const float* __restrict__ b2,
    const float* __restrict__ W3, const float* __restrict__ b3,
    float* __restrict__ out)           // [512,10]
{
    __shared__ __align__(16) _Float16       planes[8][2][2][PR][PC]; // 113,152 B
    __shared__ __align__(16) unsigned short wtbl[8][2][7][48];       //  10,752 B
    __shared__ __align__(16) float          mlp2[2][640];            //   5,120 B

    const int b0   = blockIdx.x * 2;   // image pair
    const int tid  = threadIdx.x;
    const int f    = tid >> 6;
    const int lane = tid & 63;
    const int n15  = lane & 15;
    const int q    = lane >> 4;

    _Float16 (*ev0)[PC] = planes[f][0][0];
    _Float16 (*pv0)[PC] = planes[f][0][1];
    _Float16 (*ev1)[PC] = planes[f][1][0];
    _Float16 (*pv1)[PC] = planes[f][1][1];
    const float* src0 = x + (size_t)b0 * NPIX;
    const float* src1 = src0 + NPIX;

    const float a1 = sa[f * 2 + 0];
    const float a2 = sa[f * 2 + 1];

    unsigned wp1 = 0, wp2 = 0;
    if (lane < 49) {
        union { _Float16 h[2]; unsigned u; } p;
        float w1v = sw[(f * 2 + 0) * 49 + lane];
        float e1  = __expf(a1 * w1v);
        p.h[0] = (_Float16)(w1v * e1);
        p.h[1] = (_Float16)e1;
        wp1 = p.u;
        float w2v = sw[(f * 2 + 1) * 49 + lane];
        float e2  = __expf(a2 * w2v);
        p.h[0] = (_Float16)(w2v * e2);
        p.h[1] = (_Float16)e2;
        wp2 = p.u;
    }

    {
        unsigned* tz = (unsigned*)&wtbl[f][0][0][0];   // 336 uints
        for (int i = lane; i < 336; i += 64) tz[i] = 0;
    }
    if (lane < 49) {
        int di = lane / 7, t = lane - di * 7;
        wtbl[f][0][di][16 + t] = (unsigned short)(wp1 & 0xFFFF);   // qw
        wtbl[f][1][di][16 + t] = (unsigned short)(wp1 >> 16);      // ew
    }

    {
        unsigned* e0u = (unsigned*)&planes[f][0][0][0][0];
        unsigned* p0u = (unsigned*)&planes[f][0][1][0][0];
        unsigned* e1u = (unsigned*)&planes[f][1][0][0][0];
        unsigned* p1u = (unsigned*)&planes[f][1][1][0][0];
        for (int i = lane; i < PLANE / 2; i += 64) {
            e0u[i] = 0x3C003C00u; p0u[i] = 0u;
            e1u[i] = 0x3C003C00u; p1u[i] = 0u;
        }
    }

#pragma unroll
    for (int k = 0; k < 13; ++k) {
        int p = lane + 64 * k;
        if (p < NPIX) {
            float v0 = src0[p];
            float v1 = src1[p];
            int pi = p / HW;
            int pj = p - pi * HW;
            float e0 = __expf(a1 * v0);
            float e1 = __expf(a1 * v1);
            ev0[pi + 3][pj + 3] = (_Float16)e0;
            pv0[pi + 3][pj + 3] = (_Float16)(v0 * e0);
            ev1[pi + 3][pj + 3] = (_Float16)e1;
            pv1[pi + 3][pj + 3] = (_Float16)(v1 * e1);
        }
    }

    // ===== W1 REGISTER PREFETCH: issued here (younger than pack loads, so
    // pack's waitcnts don't drain them); latency hides under conv1; consumed
    // after pool. 25 float4 = 100 VGPR (cap 256 at launch_bounds(512,1)).
    // Fully unrolled -> static indexing (no scratch).
    const int n1  = tid >> 2;
    const int h1i = tid & 3;
    float4 w1r[25];
    if (tid < 480) {
        const float4* wr1 = (const float4*)(W1 + n1 * 392);
#pragma unroll
        for (int i = 0; i < 25; ++i) {
            int k = h1i + 4 * i;
            if (k < 98) w1r[i] = wr1[k];
        }
    }
    // ========================================================================

    // ---- stage 1 conv (MFMA, both images) ----
    f32x4 o1_[2][2][2];
    mconv2(ev0, pv0, ev1, pv1, wtbl[f], q, n15, o1_);

#pragma unroll
    for (int rt = 0; rt < 2; ++rt)
#pragma unroll
        for (int ct = 0; ct < 2; ++ct) {
            if (ct == 1 && n15 >= 12) continue;
#pragma unroll
            for (int v = 0; v < 4; ++v) {
                int row = rt * 12 + 4 * q + v;
                int col = ct * 16 + n15;
                float ova = o1_[0][rt][ct][v];
                float ovb = o1_[1][rt][ct][v];
                float ea  = __expf(a2 * ova);
                float eb  = __expf(a2 * ovb);
                ev0[row + 3][col + 3] = (_Float16)ea;
                pv0[row + 3][col + 3] = (_Float16)(ova * ea);
                ev1[row + 3][col + 3] = (_Float16)eb;
                pv1[row + 3][col + 3] = (_Float16)(ovb * eb);
            }
        }

    if (lane < 49) {
        int di = lane / 7, t = lane - di * 7;
        wtbl[f][0][di][16 + t] = (unsigned short)(wp2 & 0xFFFF);
        wtbl[f][1][di][16 + t] = (unsigned short)(wp2 >> 16);
    }

    // ---- stage 2 conv (MFMA, both images) ----
    f32x4 o2_[2][2][2];
    mconv2(ev0, pv0, ev1, pv1, wtbl[f], q, n15, o2_);

    float* feat0 = mlp2[0];
    float* feat1 = mlp2[1];

#pragma unroll
    for (int rt = 0; rt < 2; ++rt)
#pragma unroll
        for (int ct = 0; ct < 2; ++ct) {
            float s0 = o2_[0][rt][ct][0] + o2_[0][rt][ct][1] + o2_[0][rt][ct][2] + o2_[0][rt][ct][3];
            float s1 = o2_[1][rt][ct][0] + o2_[1][rt][ct][1] + o2_[1][rt][ct][2] + o2_[1][rt][ct][3];
            s0 += __shfl_xor(s0, 1);  s1 += __shfl_xor(s1, 1);
            s0 += __shfl_xor(s0, 2);  s1 += __shfl_xor(s1, 2);
            int pr = rt ? (3 + q) : q;
            int pc = (ct ? 4 : 0) + (n15 >> 2);
            bool ok = ((n15 & 3) == 0)
                   && !(rt == 1 && q == 0)
                   && !(ct == 1 && n15 >= 12);
            if (ok) {
                feat0[f * 49 + pr * 7 + pc] = s0 * 0.0625f;
                feat1[f * 49 + pr * 7 + pc] = s1 * 0.0625f;
            }
        }
    __syncthreads();

    float* h1_0 = mlp2[0] + 392;  float* h2_0 = mlp2[0] + 512;
    float* h1_1 = mlp2[1] + 392;  float* h2_1 = mlp2[1] + 512;

    if (tid < 480) {
        const float4* f0 = (const float4*)feat0;
        const float4* f1 = (const float4*)feat1;
        float a00 = 0.f, a01 = 0.f, a02 = 0.f, a03 = 0.f;
        float a10 = 0.f, a11 = 0.f, a12 = 0.f, a13 = 0.f;
#pragma unroll
        for (int i = 0; i < 25; ++i) {
            int k = h1i + 4 * i;
            if (k < 98) {
                float4 w  = w1r[i];
                float4 u0 = f0[k];
                float4 u1 = f1[k];
                a00 = fmaf(w.x, u0.x, a00);  a10 = fmaf(w.x, u1.x, a10);
                a01 = fmaf(w.y, u0.y, a01);  a11 = fmaf(w.y, u1.y, a11);
                a02 = fmaf(w.z, u0.z, a02);  a12 = fmaf(w.z, u1.z, a12);
                a03 = fmaf(w.w, u0.w, a03);  a13 = fmaf(w.w, u1.w, a13);
            }
        }
        float acc0 = (a00 + a01) + (a02 + a03);
        float acc1 = (a10 + a11) + (a12 + a13);
        acc0 += __shfl_xor(acc0, 1);  acc1 += __shfl_xor(acc1, 1);
        acc0 += __shfl_xor(acc0, 2);  acc1 += __shfl_xor(acc1, 2);
        if (h1i == 0) {
            h1_0[n1] = sigmoidf_(acc0 + b1[n1]);
            h1_1[n1] = sigmoidf_(acc1 + b1[n1]);
        }
    }
    __syncthreads();

    if (tid < 336) {
        int n = tid >> 2, h = tid & 3;
        const float4* wr = (const float4*)(W2 + n * 120);
        const float4* v0 = (const float4*)h1_0;
        const float4* v1 = (const float4*)h1_1;
        float a00 = 0.f, a01 = 0.f, a02 = 0.f, a03 = 0.f;
        float a10 = 0.f, a11 = 0.f, a12 = 0.f, a13 = 0.f;
        for (int k = h; k < 30; k += 4) {
            float4 w  = wr[k];
            float4 u0 = v0[k];
            float4 u1 = v1[k];
            a00 = fmaf(w.x, u0.x, a00);  a10 = fmaf(w.x, u1.x, a10);
            a01 = fmaf(w.y, u0.y, a01);  a11 = fmaf(w.y, u1.y, a11);
            a02 = fmaf(w.z, u0.z, a02);  a12 = fmaf(w.z, u1.z, a12);
            a03 = fmaf(w.w, u0.w, a03);  a13 = fmaf(w.w, u1.w, a13);
        }
        float acc0 = (a00 + a01) + (a02 + a03);
        float acc1 = (a10 + a11) + (a12 + a13);
        acc0 += __shfl_xor(acc0, 1);  acc1 += __shfl_xor(acc1, 1);
        acc0 += __shfl_xor(acc0, 2);  acc1 += __shfl_xor(acc1, 2);
        if (h == 0) {
            h2_0[n] = sigmoidf_(acc0 + b2[n]);
            h2_1[n] = sigmoidf_(acc1 + b2[n]);
        }
    }
    __syncthreads();

    if (tid < 40) {
        int n = tid >> 2, qh = tid & 3;
        const float4* wr = (const float4*)(W3 + n * 84);
        const float4* v0 = (const float4*)h2_0;
        const float4* v1 = (const float4*)h2_1;
        float a00 = 0.f, a01 = 0.f, a02 = 0.f, a03 = 0.f;
        float a10 = 0.f, a11 = 0.f, a12 = 0.f, a13 = 0.f;
        for (int k = qh; k < 21; k += 4) {
            float4 w  = wr[k];
            float4 u0 = v0[k];
            float4 u1 = v1[k];
            a00 = fmaf(w.x, u0.x, a00);  a10 = fmaf(w.x, u1.x, a10);
            a01 = fmaf(w.y, u0.y, a01);  a11 = fmaf(w.y, u1.y, a11);
            a02 = fmaf(w.z, u0.z, a02);  a12 = fmaf(w.z, u1.z, a12);
            a03 = fmaf(w.w, u0.w, a03);  a13 = fmaf(w.w, u1.w, a13);
        }
        float acc0 = (a00 + a01) + (a02 + a03);
        float acc1 = (a10 + a11) + (a12 + a13);
        acc0 += __shfl_xor(acc0, 1);  acc1 += __shfl_xor(acc1, 1);
        acc0 += __shfl_xor(acc0, 2);  acc1 += __shfl_xor(acc1, 2);
        if (qh == 0) {
            out[(size_t)b0 * 10 + n]       = sigmoidf_(acc0 + b3[n]);
            out[(size_t)(b0 + 1) * 10 + n] = sigmoidf_(acc1 + b3[n]);
        }
    }
}

extern "C" void kernel_launch(void* const* d_in, const int* in_sizes, int n_in,
                              void* d_out, int out_size, void* d_ws, size_t ws_size,
                              hipStream_t stream) {
    const float* x  = (const float*)d_in[0];
    const float* sw = (const float*)d_in[1];
    const float* sa = (const float*)d_in[2];
    const float* W1 = (const float*)d_in[3];
    const float* b1 = (const float*)d_in[4];
    const float* W2 = (const float*)d_in[5];
    const float* b2 = (const float*)d_in[6];
    const float* W3 = (const float*)d_in[7];
    const float* b3 = (const float*)d_in[8];
    float* out = (float*)d_out;

    smorph_net_kernel<<<NBLK, 512, 0, stream>>>(x, sw, sa, W1, b1, W2, b2, W3, b3, out);
}